// Round 6
// baseline (546.696 us; speedup 1.0000x reference)
//
#include <hip/hip_runtime.h>
#include <cstdint>
#include <cstddef>

typedef float floatx4 __attribute__((ext_vector_type(4)));
typedef short bf16x8 __attribute__((ext_vector_type(8)));

#define MFMA(a, b, c) __builtin_amdgcn_mfma_f32_16x16x32_bf16((a), (b), (c), 0, 0, 0)

__device__ __forceinline__ unsigned short f2bf(float f) {
  union { float f; unsigned int u; } v; v.f = f;
  unsigned int u = v.u;
  unsigned int r = (u + 0x7FFFu + ((u >> 16) & 1u)) >> 16;
  return (unsigned short)r;
}

__device__ __forceinline__ void gload_lds16(const unsigned short* g, unsigned short* s) {
  __builtin_amdgcn_global_load_lds(
      (const __attribute__((address_space(1))) unsigned int*)g,
      (__attribute__((address_space(3))) unsigned int*)s, 16, 0, 0);
}

__device__ __forceinline__ float gelu_f(float v) {
  float z = 0.7978845608028654f * (v + 0.044715f * v * v * v);
  float e = __expf(2.0f * z);
  float th = 1.0f - 2.0f / (e + 1.0f);
  return 0.5f * v * (1.0f + th);
}

// ------------------------------------------------------------------
// Fused prep: 6 weight transposes (ids 0..12287) + RMSNorm rows
// (ids 12288..20479).  Transpose: src [R,C] fp32 -> dst [C,R] bf16.
// ------------------------------------------------------------------
__global__ __launch_bounds__(256) void prep_all(
    const float* __restrict__ w_mlp_in, const float* __restrict__ wq,
    const float* __restrict__ wk, const float* __restrict__ wv,
    const float* __restrict__ w_mlp_out, const float* __restrict__ w_attn_out,
    const float* __restrict__ x, const float* __restrict__ pns,
    unsigned short* __restrict__ wcatT, unsigned short* __restrict__ wcat2T,
    unsigned short* __restrict__ xn) {
  __shared__ float tile[32][33];
  __shared__ float ws4[4];
  int id = blockIdx.x;
  if (id >= 12288) {
    // ---- RMSNorm row
    int row = id - 12288;
    const float4 v = ((const float4*)(x + (size_t)row * 1024))[threadIdx.x];
    float ss = v.x * v.x + v.y * v.y + v.z * v.z + v.w * v.w;
#pragma unroll
    for (int off = 1; off < 64; off <<= 1) ss += __shfl_xor(ss, off, 64);
    if ((threadIdx.x & 63) == 0) ws4[threadIdx.x >> 6] = ss;
    __syncthreads();
    float tot = ws4[0] + ws4[1] + ws4[2] + ws4[3];
    float rs = rsqrtf(tot * (1.0f / 1024.0f) + 1e-6f);
    const float4 sc = ((const float4*)pns)[threadIdx.x];
    uint2 o;
    o.x = (unsigned)f2bf(v.x * rs * sc.x) | ((unsigned)f2bf(v.y * rs * sc.y) << 16);
    o.y = (unsigned)f2bf(v.z * rs * sc.z) | ((unsigned)f2bf(v.w * rs * sc.w) << 16);
    ((uint2*)(xn + (size_t)row * 1024))[threadIdx.x] = o;
    return;
  }
  // ---- transpose tile
  const float* src; unsigned short* dst; int C, ldd, bx, by, q;
  if (id < 4096)       { src = w_mlp_in;   dst = wcatT;                        C = 4096; ldd = 1024; q = id;         bx = q & 127; by = q >> 7; }
  else if (id < 5120)  { src = wq;         dst = wcatT + (size_t)4096 * 1024;  C = 1024; ldd = 1024; q = id - 4096;  bx = q & 31;  by = q >> 5; }
  else if (id < 6144)  { src = wk;         dst = wcatT + (size_t)5120 * 1024;  C = 1024; ldd = 1024; q = id - 5120;  bx = q & 31;  by = q >> 5; }
  else if (id < 7168)  { src = wv;         dst = wcatT + (size_t)6144 * 1024;  C = 1024; ldd = 1024; q = id - 6144;  bx = q & 31;  by = q >> 5; }
  else if (id < 11264) { src = w_mlp_out;  dst = wcat2T;                       C = 1024; ldd = 5120; q = id - 7168;  bx = q & 31;  by = q >> 5; }
  else                 { src = w_attn_out; dst = wcat2T + 4096;                C = 1024; ldd = 5120; q = id - 11264; bx = q & 31;  by = q >> 5; }
  int tx = threadIdx.x & 31, ty = threadIdx.x >> 5;
#pragma unroll
  for (int i = 0; i < 4; i++) {
    int r = ty + i * 8;
    tile[r][tx] = src[(size_t)(by * 32 + r) * C + bx * 32 + tx];
  }
  __syncthreads();
#pragma unroll
  for (int i = 0; i < 4; i++) {
    int r = ty + i * 8;
    dst[(size_t)(bx * 32 + r) * ldd + by * 32 + tx] = f2bf(tile[tx][r]);
  }
}

// ------------------------------------------------------------------
// GEMM: C[M,N] = A[M,K] * BT[N,K]^T (both bf16, K-major).  128x128
// tile, BK=64 as 2 x 32-k sub-buffers, 4 waves x 64x64.
//
// nt-stores on all epilogue writes (R5, proven -21us): gemm6's
// streaming writes were evicting the per-XCD B-panel from L2 (FETCH
// 160 -> 113 MB ~= XCD-partition ideal).  Cost: partial-line HBM
// write amplification (WRITE 139 -> 214 MB) -- net win.
// f2bf (not cvt_pk) everywhere: cvt_pk rounding tripled absmax.
//
// HYBRID SWIZZLE (0 bank conflicts measured): staging lane L ->
// (row L>>2, granule (L&3)^((L>>3)&3)); frag read
// fo=(4*l15+(quad^((l15>>1)&3)))*8.
// ------------------------------------------------------------------
template <int MODE>
__global__ __launch_bounds__(256, 2) void gemm_bt(
    const unsigned short* __restrict__ A, const unsigned short* __restrict__ BT,
    int K, void* __restrict__ outp,
    const float* __restrict__ bias1, const float* __restrict__ bias2,
    const float* __restrict__ resid,
    int msplit, int tm, int tn,
    unsigned short* __restrict__ q_out, unsigned short* __restrict__ k_out,
    unsigned short* __restrict__ v_out) {
  __shared__ unsigned short As[2][128 * 32];
  __shared__ unsigned short Bs[2][128 * 32];

  int id = blockIdx.x + gridDim.x * blockIdx.y;
  int xcd = id & 7, j = id >> 3;
  int mh = xcd % msplit, nq = xcd / msplit;
  int by = mh * tm + j / tn;
  int bx = nq * tn + j % tn;
  int m0 = by * 128, n0 = bx * 128;

  int t = threadIdx.x, lane = t & 63, wave = t >> 6;
  int l15 = lane & 15, quad = lane >> 4;
  int wm = (wave & 1) * 64, wn = (wave >> 1) * 64;

  floatx4 acc[4][4] = {};

  int lr = lane >> 2;
  int lg = (lane & 3) ^ ((lane >> 3) & 3);
  int ch0 = wave * 2, ch1 = wave * 2 + 1;
  const unsigned short* gA0 = A + (size_t)(m0 + ch0 * 16 + lr) * K + lg * 8;
  const unsigned short* gA1 = A + (size_t)(m0 + ch1 * 16 + lr) * K + lg * 8;
  const unsigned short* gB0 = BT + (size_t)(n0 + ch0 * 16 + lr) * K + lg * 8;
  const unsigned short* gB1 = BT + (size_t)(n0 + ch1 * 16 + lr) * K + lg * 8;
  unsigned short* sA0[2] = {&As[0][ch0 * 512 + lane * 8], &As[1][ch0 * 512 + lane * 8]};
  unsigned short* sA1[2] = {&As[0][ch1 * 512 + lane * 8], &As[1][ch1 * 512 + lane * 8]};
  unsigned short* sB0[2] = {&Bs[0][ch0 * 512 + lane * 8], &Bs[1][ch0 * 512 + lane * 8]};
  unsigned short* sB1[2] = {&Bs[0][ch1 * 512 + lane * 8], &Bs[1][ch1 * 512 + lane * 8]};

  int fo = (4 * l15 + (quad ^ ((l15 >> 1) & 3))) * 8;
  int ca = (wm >> 4);
  int cb = (wn >> 4);

  for (int kt = 0; kt < K; kt += 64) {
    __syncthreads();
#pragma unroll
    for (int kk = 0; kk < 2; kk++) {
      int kg = kt + kk * 32;
      gload_lds16(gA0 + kg, sA0[kk]);
      gload_lds16(gA1 + kg, sA1[kk]);
      gload_lds16(gB0 + kg, sB0[kk]);
      gload_lds16(gB1 + kg, sB1[kk]);
    }
    __syncthreads();
#pragma unroll
    for (int kk = 0; kk < 2; kk++) {
      bf16x8 a[4], b[4];
#pragma unroll
      for (int im = 0; im < 4; im++)
        a[im] = *(const bf16x8*)&As[kk][(ca + im) * 512 + fo];
#pragma unroll
      for (int in_ = 0; in_ < 4; in_++)
        b[in_] = *(const bf16x8*)&Bs[kk][(cb + in_) * 512 + fo];
#pragma unroll
      for (int im = 0; im < 4; im++)
#pragma unroll
        for (int in_ = 0; in_ < 4; in_++)
          acc[im][in_] = MFMA(a[im], b[in_], acc[im][in_]);
    }
  }

#pragma unroll
  for (int im = 0; im < 4; im++) {
#pragma unroll
    for (int in_ = 0; in_ < 4; in_++) {
      int row0 = m0 + wm + im * 16 + quad * 4;
      int col = n0 + wn + in_ * 16 + l15;
      if constexpr (MODE == 6) {
        if (n0 < 4096) {
#pragma unroll
          for (int r = 0; r < 4; r++) {
            __builtin_nontemporal_store(f2bf(gelu_f(acc[im][in_][r])),
                &((unsigned short*)outp)[(size_t)(row0 + r) * 5120 + col]);
          }
        } else {
          int seg = (n0 - 4096) >> 10;          // 0=q 1=k 2=v (tile-uniform)
          int cs = col - 4096 - (seg << 10);
          int h = cs >> 6, hd = cs & 63;
          int b_ = row0 >> 11, s0 = row0 & 2047;
          if (seg == 2) {
            // s-consecutive: pack 4 bf16 -> one 64-bit store
            unsigned long long o =
                (unsigned long long)((unsigned)f2bf(acc[im][in_][0]) |
                                     ((unsigned)f2bf(acc[im][in_][1]) << 16)) |
                ((unsigned long long)((unsigned)f2bf(acc[im][in_][2]) |
                                      ((unsigned)f2bf(acc[im][in_][3]) << 16)) << 32);
            __builtin_nontemporal_store(o,
                (unsigned long long*)&v_out[(((size_t)(b_ * 16 + h)) * 64 + hd) * 2048 + s0]);
          } else {
            float sc = (seg == 0) ? 0.125f : 1.0f;
            unsigned short* dst = (seg == 0) ? q_out : k_out;
#pragma unroll
            for (int r = 0; r < 4; r++) {
              __builtin_nontemporal_store(f2bf(acc[im][in_][r] * sc),
                  &dst[(((size_t)(b_ * 16 + h)) * 2048 + s0 + r) * 64 + hd]);
            }
          }
        }
      } else {
        float bsum = bias1[col] + bias2[col];
#pragma unroll
        for (int r = 0; r < 4; r++) {
          size_t idx = (size_t)(row0 + r) * 1024 + col;
          float res = __builtin_nontemporal_load(&resid[idx]);
          __builtin_nontemporal_store(acc[im][in_][r] + bsum + res, &((float*)outp)[idx]);
        }
      }
    }
  }
}

// ------------------------------------------------------------------
// Flash attention, no-max additive variant.  q pre-scaled by 0.125.
// q,k [B,H,S,HD]; v [B,H,HD,S] bf16.  av -> cat cols 4096..5120.
// 4 waves x 32 q rows; kv tile 64; double-buffered K/V.
//
// R6: per-iter barrier is now lgkmcnt(0) + raw s_barrier (NOT
// __syncthreads, which compiles to s_waitcnt vmcnt(0) lgkmcnt(0) +
// s_barrier and therefore DRAINED the t+2 register prefetch at every
// iteration -- all waves stalled on the newest HBM loads each iter).
// lgkmcnt(0) per wave guarantees this wave's staging ds_writes to
// buf^1 completed (cross-wave visibility after the barrier); read
// WARs need nothing extra (consuming MFMAs already issued => reads
// complete).  Global loads stay in flight across barriers; compiler
// inserts the vmcnt wait only at the ds_write that consumes the
// loaded register next iter.
// LK/LV/LP=68: LDS 52224 B -> 3 blocks/CU; launch_bounds(256,3).
// ------------------------------------------------------------------
__global__ __launch_bounds__(256, 3) void flash_attn(
    const unsigned short* __restrict__ q_buf, const unsigned short* __restrict__ k_buf,
    const unsigned short* __restrict__ v_buf, unsigned short* __restrict__ cat) {
  constexpr int S = 2048, HD = 64;
  constexpr int LK = 68, LV = 68, LP = 68;
  __shared__ unsigned short Ks[2][64 * LK];
  __shared__ unsigned short Vs[2][64 * LV];
  __shared__ unsigned short Ps[4][32 * LP];

  int id = blockIdx.x + gridDim.x * blockIdx.y;   // grid (16, 64)
  int xcd = id & 7, j = id >> 3;                  // j in [0,128)
  int bh = xcd * 8 + (j >> 4);
  int qbk = j & 15;

  int t = threadIdx.x, lane = t & 63, wave = t >> 6;
  int l15 = lane & 15, quad = lane >> 4;

  const unsigned short* qp = q_buf + (size_t)bh * S * HD;
  const unsigned short* kp = k_buf + (size_t)bh * S * HD;
  const unsigned short* vp = v_buf + (size_t)bh * HD * S;

  int q0 = qbk * 128 + wave * 32;
  bf16x8 aQ[2][2];
#pragma unroll
  for (int qf = 0; qf < 2; qf++) {
    aQ[qf][0] = *(const bf16x8*)&qp[(size_t)(q0 + qf * 16 + l15) * HD + quad * 8];
    aQ[qf][1] = *(const bf16x8*)&qp[(size_t)(q0 + qf * 16 + l15) * HD + 32 + quad * 8];
  }

  floatx4 acc_o[2][4] = {};
  float lrow[2][4] = {};

  int kr = t >> 3, kc = (t & 7) * 8;

  // tile 0 -> regs -> buf0
  uint4 rK0 = *(const uint4*)&kp[(size_t)kr * HD + kc];
  uint4 rK1 = *(const uint4*)&kp[(size_t)(kr + 32) * HD + kc];
  uint4 rV0 = *(const uint4*)&vp[(size_t)kr * S + kc];
  uint4 rV1 = *(const uint4*)&vp[(size_t)(kr + 32) * S + kc];
  *(uint4*)&Ks[0][kr * LK + kc] = rK0;
  *(uint4*)&Ks[0][(kr + 32) * LK + kc] = rK1;
  *(uint4*)&Vs[0][kr * LV + kc] = rV0;
  *(uint4*)&Vs[0][(kr + 32) * LV + kc] = rV1;
  // prefetch tile 1 -> regs (stays in flight across the barrier)
  rK0 = *(const uint4*)&kp[(size_t)(64 + kr) * HD + kc];
  rK1 = *(const uint4*)&kp[(size_t)(64 + kr + 32) * HD + kc];
  rV0 = *(const uint4*)&vp[(size_t)kr * S + 64 + kc];
  rV1 = *(const uint4*)&vp[(size_t)(kr + 32) * S + 64 + kc];
  asm volatile("s_waitcnt lgkmcnt(0)" ::: "memory");
  __builtin_amdgcn_s_barrier();
  __builtin_amdgcn_sched_barrier(0);

  for (int kv = 0; kv < S; kv += 64) {
    int cur = (kv >> 6) & 1;
    // stage tile t+1 regs -> buf^1 (overlaps with QK^T below);
    // compiler inserts the vmcnt wait for the prefetch loads here.
    if (kv + 64 < S) {
      *(uint4*)&Ks[cur ^ 1][kr * LK + kc] = rK0;
      *(uint4*)&Ks[cur ^ 1][(kr + 32) * LK + kc] = rK1;
      *(uint4*)&Vs[cur ^ 1][kr * LV + kc] = rV0;
      *(uint4*)&Vs[cur ^ 1][(kr + 32) * LV + kc] = rV1;
    }

    floatx4 z[2][4];
#pragma unroll
    for (int cg = 0; cg < 4; cg++) {
      bf16x8 bk0 = *(const bf16x8*)&Ks[cur][(cg * 16 + l15) * LK + quad * 8];
      bf16x8 bk1 = *(const bf16x8*)&Ks[cur][(cg * 16 + l15) * LK + 32 + quad * 8];
#pragma unroll
      for (int qf = 0; qf < 2; qf++) {
        floatx4 acc = {};
        acc = MFMA(aQ[qf][0], bk0, acc);
        acc = MFMA(aQ[qf][1], bk1, acc);
        z[qf][cg] = acc;
      }
    }
    // prefetch tile t+2 -> regs
    if (kv + 128 < S) {
      rK0 = *(const uint4*)&kp[(size_t)(kv + 128 + kr) * HD + kc];
      rK1 = *(const uint4*)&kp[(size_t)(kv + 128 + kr + 32) * HD + kc];
      rV0 = *(const uint4*)&vp[(size_t)kr * S + kv + 128 + kc];
      rV1 = *(const uint4*)&vp[(size_t)(kr + 32) * S + kv + 128 + kc];
    }
#pragma unroll
    for (int qf = 0; qf < 2; qf++)
#pragma unroll
      for (int cg = 0; cg < 4; cg++)
#pragma unroll
        for (int r = 0; r < 4; r++) {
          float e = __expf(z[qf][cg][r]);
          lrow[qf][r] += e;
          Ps[wave][(qf * 16 + quad * 4 + r) * LP + cg * 16 + l15] = f2bf(e);
        }
    asm volatile("s_waitcnt lgkmcnt(0)" ::: "memory");
#pragma unroll
    for (int c = 0; c < 2; c++) {
      bf16x8 aP[2];
#pragma unroll
      for (int qf = 0; qf < 2; qf++) {
        const unsigned short* pp = &Ps[wave][(qf * 16 + l15) * LP + c * 32 + quad * 8];
        ((uint2*)&aP[qf])[0] = *(const uint2*)pp;
        ((uint2*)&aP[qf])[1] = *(const uint2*)(pp + 4);
      }
#pragma unroll
      for (int n = 0; n < 4; n++) {
        bf16x8 bv = *(const bf16x8*)&Vs[cur][(n * 16 + l15) * LV + c * 32 + quad * 8];
        acc_o[0][n] = MFMA(aP[0], bv, acc_o[0][n]);
        acc_o[1][n] = MFMA(aP[1], bv, acc_o[1][n]);
      }
    }
    // LDS-only barrier: staging writes visible cross-wave; vmem
    // prefetch loads remain in flight.
    asm volatile("s_waitcnt lgkmcnt(0)" ::: "memory");
    __builtin_amdgcn_s_barrier();
    __builtin_amdgcn_sched_barrier(0);
  }

#pragma unroll
  for (int qf = 0; qf < 2; qf++)
#pragma unroll
    for (int r = 0; r < 4; r++) {
      float s = lrow[qf][r];
#pragma unroll
      for (int off = 1; off < 16; off <<= 1) s += __shfl_xor(s, off, 16);
      lrow[qf][r] = s;
    }

  int b_ = bh >> 4, h = bh & 15;
#pragma unroll
  for (int qf = 0; qf < 2; qf++)
#pragma unroll
    for (int r = 0; r < 4; r++) {
      float inv = 1.0f / lrow[qf][r];
      int srow = q0 + qf * 16 + quad * 4 + r;
      size_t base = ((size_t)(b_ * 2048 + srow)) * 5120 + 4096 + h * 64;
#pragma unroll
      for (int n = 0; n < 4; n++)
        __builtin_nontemporal_store(f2bf(acc_o[qf][n][r] * inv),
                                    &cat[base + n * 16 + l15]);
    }
}

// ------------------------------------------------------------------
extern "C" void kernel_launch(void* const* d_in, const int* in_sizes, int n_in,
                              void* d_out, int out_size, void* d_ws, size_t ws_size,
                              hipStream_t stream) {
  (void)in_sizes; (void)n_in; (void)out_size; (void)ws_size;
  const float* x          = (const float*)d_in[0];
  const float* pns        = (const float*)d_in[1];
  const float* w_mlp_in   = (const float*)d_in[2];
  const float* wq         = (const float*)d_in[3];
  const float* wk         = (const float*)d_in[4];
  const float* wv         = (const float*)d_in[5];
  const float* w_mlp_out  = (const float*)d_in[6];
  const float* b_mlp_out  = (const float*)d_in[7];
  const float* w_attn_out = (const float*)d_in[8];
  const float* b_attn_out = (const float*)d_in[9];
  float* out = (float*)d_out;

  char* ws = (char*)d_ws;
  size_t off = 0;
  auto alloc = [&](size_t bytes) {
    void* p = ws + off;
    off += (bytes + 255) & ~(size_t)255;
    return p;
  };
  const size_t M = 8192;
  unsigned short* xn     = (unsigned short*)alloc(M * 1024 * 2);
  unsigned short* wcatT  = (unsigned short*)alloc((size_t)7168 * 1024 * 2);  // [mlp_in|q|k|v][N,K]
  unsigned short* wcat2T = (unsigned short*)alloc((size_t)1024 * 5120 * 2);  // [N=1024, K=5120]
  unsigned short* cat    = (unsigned short*)alloc(M * 5120 * 2);             // [h | av]
  unsigned short* qb     = (unsigned short*)alloc(M * 1024 * 2);
  unsigned short* kb     = (unsigned short*)alloc(M * 1024 * 2);
  unsigned short* vb     = (unsigned short*)alloc(M * 1024 * 2);

  // fused transposes + rmsnorm (independent; both feed gemm6)
  prep_all<<<dim3(20480), 256, 0, stream>>>(
      w_mlp_in, wq, wk, wv, w_mlp_out, w_attn_out, x, pns, wcatT, wcat2T, xn);

  // fused input GEMM: [8192,1024] x [7168,1024]^T; 128x128 tiles,
  // grid 56x64 = 3584 blocks; msplit=2 nsplit=4 (tn=14)
  gemm_bt<6><<<dim3(56, 64), 256, 0, stream>>>(
      xn, wcatT, 1024, cat, nullptr, nullptr, nullptr, 2, 32, 14, qb, kb, vb);

  flash_attn<<<dim3(16, 64), 256, 0, stream>>>(qb, kb, vb, cat);

  // fused output GEMM: [8192,5120] x [1024,5120]^T; 128x128 tiles,
  // grid 8x64 = 512 blocks; msplit=2 nsplit=4 (tn=2)
  gemm_bt<7><<<dim3(8, 64), 256, 0, stream>>>(
      cat, wcat2T, 5120, out, b_mlp_out, b_attn_out, x, 2, 32, 2, nullptr, nullptr, nullptr);
}

// Round 7
// 520.694 us; speedup vs baseline: 1.0499x; 1.0499x over previous
//
#include <hip/hip_runtime.h>
#include <cstdint>
#include <cstddef>

typedef float floatx4 __attribute__((ext_vector_type(4)));
typedef short bf16x8 __attribute__((ext_vector_type(8)));

#define MFMA(a, b, c) __builtin_amdgcn_mfma_f32_16x16x32_bf16((a), (b), (c), 0, 0, 0)

__device__ __forceinline__ unsigned short f2bf(float f) {
  union { float f; unsigned int u; } v; v.f = f;
  unsigned int u = v.u;
  unsigned int r = (u + 0x7FFFu + ((u >> 16) & 1u)) >> 16;
  return (unsigned short)r;
}

__device__ __forceinline__ void gload_lds16(const unsigned short* g, unsigned short* s) {
  __builtin_amdgcn_global_load_lds(
      (const __attribute__((address_space(1))) unsigned int*)g,
      (__attribute__((address_space(3))) unsigned int*)s, 16, 0, 0);
}

__device__ __forceinline__ float gelu_f(float v) {
  float z = 0.7978845608028654f * (v + 0.044715f * v * v * v);
  float e = __expf(2.0f * z);
  float th = 1.0f - 2.0f / (e + 1.0f);
  return 0.5f * v * (1.0f + th);
}

// ------------------------------------------------------------------
// Fused prep: 6 weight transposes (ids 0..12287) + RMSNorm rows
// (ids 12288..20479).  Transpose: src [R,C] fp32 -> dst [C,R] bf16.
// ------------------------------------------------------------------
__global__ __launch_bounds__(256) void prep_all(
    const float* __restrict__ w_mlp_in, const float* __restrict__ wq,
    const float* __restrict__ wk, const float* __restrict__ wv,
    const float* __restrict__ w_mlp_out, const float* __restrict__ w_attn_out,
    const float* __restrict__ x, const float* __restrict__ pns,
    unsigned short* __restrict__ wcatT, unsigned short* __restrict__ wcat2T,
    unsigned short* __restrict__ xn) {
  __shared__ float tile[32][33];
  __shared__ float ws4[4];
  int id = blockIdx.x;
  if (id >= 12288) {
    // ---- RMSNorm row
    int row = id - 12288;
    const float4 v = ((const float4*)(x + (size_t)row * 1024))[threadIdx.x];
    float ss = v.x * v.x + v.y * v.y + v.z * v.z + v.w * v.w;
#pragma unroll
    for (int off = 1; off < 64; off <<= 1) ss += __shfl_xor(ss, off, 64);
    if ((threadIdx.x & 63) == 0) ws4[threadIdx.x >> 6] = ss;
    __syncthreads();
    float tot = ws4[0] + ws4[1] + ws4[2] + ws4[3];
    float rs = rsqrtf(tot * (1.0f / 1024.0f) + 1e-6f);
    const float4 sc = ((const float4*)pns)[threadIdx.x];
    uint2 o;
    o.x = (unsigned)f2bf(v.x * rs * sc.x) | ((unsigned)f2bf(v.y * rs * sc.y) << 16);
    o.y = (unsigned)f2bf(v.z * rs * sc.z) | ((unsigned)f2bf(v.w * rs * sc.w) << 16);
    ((uint2*)(xn + (size_t)row * 1024))[threadIdx.x] = o;
    return;
  }
  // ---- transpose tile
  const float* src; unsigned short* dst; int C, ldd, bx, by, q;
  if (id < 4096)       { src = w_mlp_in;   dst = wcatT;                        C = 4096; ldd = 1024; q = id;         bx = q & 127; by = q >> 7; }
  else if (id < 5120)  { src = wq;         dst = wcatT + (size_t)4096 * 1024;  C = 1024; ldd = 1024; q = id - 4096;  bx = q & 31;  by = q >> 5; }
  else if (id < 6144)  { src = wk;         dst = wcatT + (size_t)5120 * 1024;  C = 1024; ldd = 1024; q = id - 5120;  bx = q & 31;  by = q >> 5; }
  else if (id < 7168)  { src = wv;         dst = wcatT + (size_t)6144 * 1024;  C = 1024; ldd = 1024; q = id - 6144;  bx = q & 31;  by = q >> 5; }
  else if (id < 11264) { src = w_mlp_out;  dst = wcat2T;                       C = 1024; ldd = 5120; q = id - 7168;  bx = q & 31;  by = q >> 5; }
  else                 { src = w_attn_out; dst = wcat2T + 4096;                C = 1024; ldd = 5120; q = id - 11264; bx = q & 31;  by = q >> 5; }
  int tx = threadIdx.x & 31, ty = threadIdx.x >> 5;
#pragma unroll
  for (int i = 0; i < 4; i++) {
    int r = ty + i * 8;
    tile[r][tx] = src[(size_t)(by * 32 + r) * C + bx * 32 + tx];
  }
  __syncthreads();
#pragma unroll
  for (int i = 0; i < 4; i++) {
    int r = ty + i * 8;
    dst[(size_t)(bx * 32 + r) * ldd + by * 32 + tx] = f2bf(tile[tx][r]);
  }
}

// ------------------------------------------------------------------
// GEMM: C[M,N] = A[M,K] * BT[N,K]^T (both bf16, K-major).  128x128
// tile, BK=64 as 2 x 32-k sub-buffers, 4 waves x 64x64.
// R6 version, measured 163 us MODE6 / MfmaUtil 33 / FETCH 124 MB.
//
// nt-stores on all epilogue writes: gemm6's streaming writes were
// evicting the per-XCD B-panel from L2 (FETCH 160 -> 113-124 MB ~=
// XCD-partition ideal).  Cost: partial-line HBM write amplification
// (WRITE 139 -> 214 MB) -- net win (-37us).  f2bf everywhere (cvt_pk
// rounding tripled absmax).
//
// HYBRID SWIZZLE (0 bank conflicts measured): staging lane L ->
// (row L>>2, granule (L&3)^((L>>3)&3)); frag read
// fo=(4*l15+(quad^((l15>>1)&3)))*8.
// ------------------------------------------------------------------
template <int MODE>
__global__ __launch_bounds__(256, 2) void gemm_bt(
    const unsigned short* __restrict__ A, const unsigned short* __restrict__ BT,
    int K, void* __restrict__ outp,
    const float* __restrict__ bias1, const float* __restrict__ bias2,
    const float* __restrict__ resid,
    int msplit, int tm, int tn,
    unsigned short* __restrict__ q_out, unsigned short* __restrict__ k_out,
    unsigned short* __restrict__ v_out) {
  __shared__ unsigned short As[2][128 * 32];
  __shared__ unsigned short Bs[2][128 * 32];

  int id = blockIdx.x + gridDim.x * blockIdx.y;
  int xcd = id & 7, j = id >> 3;
  int mh = xcd % msplit, nq = xcd / msplit;
  int by = mh * tm + j / tn;
  int bx = nq * tn + j % tn;
  int m0 = by * 128, n0 = bx * 128;

  int t = threadIdx.x, lane = t & 63, wave = t >> 6;
  int l15 = lane & 15, quad = lane >> 4;
  int wm = (wave & 1) * 64, wn = (wave >> 1) * 64;

  floatx4 acc[4][4] = {};

  int lr = lane >> 2;
  int lg = (lane & 3) ^ ((lane >> 3) & 3);
  int ch0 = wave * 2, ch1 = wave * 2 + 1;
  const unsigned short* gA0 = A + (size_t)(m0 + ch0 * 16 + lr) * K + lg * 8;
  const unsigned short* gA1 = A + (size_t)(m0 + ch1 * 16 + lr) * K + lg * 8;
  const unsigned short* gB0 = BT + (size_t)(n0 + ch0 * 16 + lr) * K + lg * 8;
  const unsigned short* gB1 = BT + (size_t)(n0 + ch1 * 16 + lr) * K + lg * 8;
  unsigned short* sA0[2] = {&As[0][ch0 * 512 + lane * 8], &As[1][ch0 * 512 + lane * 8]};
  unsigned short* sA1[2] = {&As[0][ch1 * 512 + lane * 8], &As[1][ch1 * 512 + lane * 8]};
  unsigned short* sB0[2] = {&Bs[0][ch0 * 512 + lane * 8], &Bs[1][ch0 * 512 + lane * 8]};
  unsigned short* sB1[2] = {&Bs[0][ch1 * 512 + lane * 8], &Bs[1][ch1 * 512 + lane * 8]};

  int fo = (4 * l15 + (quad ^ ((l15 >> 1) & 3))) * 8;
  int ca = (wm >> 4);
  int cb = (wn >> 4);

  for (int kt = 0; kt < K; kt += 64) {
    __syncthreads();
#pragma unroll
    for (int kk = 0; kk < 2; kk++) {
      int kg = kt + kk * 32;
      gload_lds16(gA0 + kg, sA0[kk]);
      gload_lds16(gA1 + kg, sA1[kk]);
      gload_lds16(gB0 + kg, sB0[kk]);
      gload_lds16(gB1 + kg, sB1[kk]);
    }
    __syncthreads();
#pragma unroll
    for (int kk = 0; kk < 2; kk++) {
      bf16x8 a[4], b[4];
#pragma unroll
      for (int im = 0; im < 4; im++)
        a[im] = *(const bf16x8*)&As[kk][(ca + im) * 512 + fo];
#pragma unroll
      for (int in_ = 0; in_ < 4; in_++)
        b[in_] = *(const bf16x8*)&Bs[kk][(cb + in_) * 512 + fo];
#pragma unroll
      for (int im = 0; im < 4; im++)
#pragma unroll
        for (int in_ = 0; in_ < 4; in_++)
          acc[im][in_] = MFMA(a[im], b[in_], acc[im][in_]);
    }
  }

#pragma unroll
  for (int im = 0; im < 4; im++) {
#pragma unroll
    for (int in_ = 0; in_ < 4; in_++) {
      int row0 = m0 + wm + im * 16 + quad * 4;
      int col = n0 + wn + in_ * 16 + l15;
      if constexpr (MODE == 6) {
        if (n0 < 4096) {
#pragma unroll
          for (int r = 0; r < 4; r++) {
            __builtin_nontemporal_store(f2bf(gelu_f(acc[im][in_][r])),
                &((unsigned short*)outp)[(size_t)(row0 + r) * 5120 + col]);
          }
        } else {
          int seg = (n0 - 4096) >> 10;          // 0=q 1=k 2=v (tile-uniform)
          int cs = col - 4096 - (seg << 10);
          int h = cs >> 6, hd = cs & 63;
          int b_ = row0 >> 11, s0 = row0 & 2047;
          if (seg == 2) {
            // s-consecutive: pack 4 bf16 -> one 64-bit store
            unsigned long long o =
                (unsigned long long)((unsigned)f2bf(acc[im][in_][0]) |
                                     ((unsigned)f2bf(acc[im][in_][1]) << 16)) |
                ((unsigned long long)((unsigned)f2bf(acc[im][in_][2]) |
                                      ((unsigned)f2bf(acc[im][in_][3]) << 16)) << 32);
            __builtin_nontemporal_store(o,
                (unsigned long long*)&v_out[(((size_t)(b_ * 16 + h)) * 64 + hd) * 2048 + s0]);
          } else {
            float sc = (seg == 0) ? 0.125f : 1.0f;
            unsigned short* dst = (seg == 0) ? q_out : k_out;
#pragma unroll
            for (int r = 0; r < 4; r++) {
              __builtin_nontemporal_store(f2bf(acc[im][in_][r] * sc),
                  &dst[(((size_t)(b_ * 16 + h)) * 2048 + s0 + r) * 64 + hd]);
            }
          }
        }
      } else {
        float bsum = bias1[col] + bias2[col];
#pragma unroll
        for (int r = 0; r < 4; r++) {
          size_t idx = (size_t)(row0 + r) * 1024 + col;
          float res = __builtin_nontemporal_load(&resid[idx]);
          __builtin_nontemporal_store(acc[im][in_][r] + bsum + res, &((float*)outp)[idx]);
        }
      }
    }
  }
}

// ------------------------------------------------------------------
// Flash attention, no-max additive variant -- R0 VERBATIM (the only
// flash config with a known-good measurement; every restructure
// since R0 regressed it: R3 dbuf +12us, R4 LK68/bounds3 +13us,
// R6 raw-barrier +21us, identified by total-minus-gemm accounting).
// q pre-scaled by 0.125.  q,k [B,H,S,HD]; v [B,H,HD,S] bf16.
// av -> cat cols 4096..5120.  4 waves x 32 q rows; kv tile 64.
// ------------------------------------------------------------------
__global__ __launch_bounds__(256, 2) void flash_attn(
    const unsigned short* __restrict__ q_buf, const unsigned short* __restrict__ k_buf,
    const unsigned short* __restrict__ v_buf, unsigned short* __restrict__ cat) {
  constexpr int S = 2048, HD = 64;
  constexpr int LK = 72, LV = 72, LP = 68;
  __shared__ unsigned short Ks[64 * LK];
  __shared__ unsigned short Vs[64 * LV];
  __shared__ unsigned short Ps[4][32 * LP];

  int id = blockIdx.x + gridDim.x * blockIdx.y;   // grid (16, 64)
  int xcd = id & 7, j = id >> 3;                  // j in [0,128)
  int bh = xcd * 8 + (j >> 4);
  int qbk = j & 15;

  int t = threadIdx.x, lane = t & 63, wave = t >> 6;
  int l15 = lane & 15, quad = lane >> 4;

  const unsigned short* qp = q_buf + (size_t)bh * S * HD;
  const unsigned short* kp = k_buf + (size_t)bh * S * HD;
  const unsigned short* vp = v_buf + (size_t)bh * HD * S;

  int q0 = qbk * 128 + wave * 32;
  bf16x8 aQ[2][2];
#pragma unroll
  for (int qf = 0; qf < 2; qf++) {
    aQ[qf][0] = *(const bf16x8*)&qp[(size_t)(q0 + qf * 16 + l15) * HD + quad * 8];
    aQ[qf][1] = *(const bf16x8*)&qp[(size_t)(q0 + qf * 16 + l15) * HD + 32 + quad * 8];
  }

  floatx4 acc_o[2][4] = {};
  float lrow[2][4] = {};

  int kr = t >> 3, kc = (t & 7) * 8;

  uint4 rK0 = *(const uint4*)&kp[(size_t)kr * HD + kc];
  uint4 rK1 = *(const uint4*)&kp[(size_t)(kr + 32) * HD + kc];
  uint4 rV0 = *(const uint4*)&vp[(size_t)kr * S + kc];
  uint4 rV1 = *(const uint4*)&vp[(size_t)(kr + 32) * S + kc];

  for (int kv = 0; kv < S; kv += 64) {
    __syncthreads();
    *(uint4*)&Ks[kr * LK + kc] = rK0;
    *(uint4*)&Ks[(kr + 32) * LK + kc] = rK1;
    *(uint4*)&Vs[kr * LV + kc] = rV0;
    *(uint4*)&Vs[(kr + 32) * LV + kc] = rV1;
    __syncthreads();
    if (kv + 64 < S) {
      rK0 = *(const uint4*)&kp[(size_t)(kv + 64 + kr) * HD + kc];
      rK1 = *(const uint4*)&kp[(size_t)(kv + 64 + kr + 32) * HD + kc];
      rV0 = *(const uint4*)&vp[(size_t)kr * S + kv + 64 + kc];
      rV1 = *(const uint4*)&vp[(size_t)(kr + 32) * S + kv + 64 + kc];
    }

    floatx4 z[2][4];
#pragma unroll
    for (int cg = 0; cg < 4; cg++) {
      bf16x8 bk0 = *(const bf16x8*)&Ks[(cg * 16 + l15) * LK + quad * 8];
      bf16x8 bk1 = *(const bf16x8*)&Ks[(cg * 16 + l15) * LK + 32 + quad * 8];
#pragma unroll
      for (int qf = 0; qf < 2; qf++) {
        floatx4 acc = {};
        acc = MFMA(aQ[qf][0], bk0, acc);
        acc = MFMA(aQ[qf][1], bk1, acc);
        z[qf][cg] = acc;
      }
    }
#pragma unroll
    for (int qf = 0; qf < 2; qf++)
#pragma unroll
      for (int cg = 0; cg < 4; cg++)
#pragma unroll
        for (int r = 0; r < 4; r++) {
          float e = __expf(z[qf][cg][r]);
          lrow[qf][r] += e;
          Ps[wave][(qf * 16 + quad * 4 + r) * LP + cg * 16 + l15] = f2bf(e);
        }
    asm volatile("s_waitcnt lgkmcnt(0)" ::: "memory");
#pragma unroll
    for (int c = 0; c < 2; c++) {
      bf16x8 aP[2];
#pragma unroll
      for (int qf = 0; qf < 2; qf++) {
        const unsigned short* pp = &Ps[wave][(qf * 16 + l15) * LP + c * 32 + quad * 8];
        ((uint2*)&aP[qf])[0] = *(const uint2*)pp;
        ((uint2*)&aP[qf])[1] = *(const uint2*)(pp + 4);
      }
#pragma unroll
      for (int n = 0; n < 4; n++) {
        bf16x8 bv = *(const bf16x8*)&Vs[(n * 16 + l15) * LV + c * 32 + quad * 8];
        acc_o[0][n] = MFMA(aP[0], bv, acc_o[0][n]);
        acc_o[1][n] = MFMA(aP[1], bv, acc_o[1][n]);
      }
    }
  }

#pragma unroll
  for (int qf = 0; qf < 2; qf++)
#pragma unroll
    for (int r = 0; r < 4; r++) {
      float s = lrow[qf][r];
#pragma unroll
      for (int off = 1; off < 16; off <<= 1) s += __shfl_xor(s, off, 16);
      lrow[qf][r] = s;
    }

  int b_ = bh >> 4, h = bh & 15;
#pragma unroll
  for (int qf = 0; qf < 2; qf++)
#pragma unroll
    for (int r = 0; r < 4; r++) {
      float inv = 1.0f / lrow[qf][r];
      int srow = q0 + qf * 16 + quad * 4 + r;
      size_t base = ((size_t)(b_ * 2048 + srow)) * 5120 + 4096 + h * 64;
#pragma unroll
      for (int n = 0; n < 4; n++)
        cat[base + n * 16 + l15] = f2bf(acc_o[qf][n][r] * inv);
    }
}

// ------------------------------------------------------------------
extern "C" void kernel_launch(void* const* d_in, const int* in_sizes, int n_in,
                              void* d_out, int out_size, void* d_ws, size_t ws_size,
                              hipStream_t stream) {
  (void)in_sizes; (void)n_in; (void)out_size; (void)ws_size;
  const float* x          = (const float*)d_in[0];
  const float* pns        = (const float*)d_in[1];
  const float* w_mlp_in   = (const float*)d_in[2];
  const float* wq         = (const float*)d_in[3];
  const float* wk         = (const float*)d_in[4];
  const float* wv         = (const float*)d_in[5];
  const float* w_mlp_out  = (const float*)d_in[6];
  const float* b_mlp_out  = (const float*)d_in[7];
  const float* w_attn_out = (const float*)d_in[8];
  const float* b_attn_out = (const float*)d_in[9];
  float* out = (float*)d_out;

  char* ws = (char*)d_ws;
  size_t off = 0;
  auto alloc = [&](size_t bytes) {
    void* p = ws + off;
    off += (bytes + 255) & ~(size_t)255;
    return p;
  };
  const size_t M = 8192;
  unsigned short* xn     = (unsigned short*)alloc(M * 1024 * 2);
  unsigned short* wcatT  = (unsigned short*)alloc((size_t)7168 * 1024 * 2);  // [mlp_in|q|k|v][N,K]
  unsigned short* wcat2T = (unsigned short*)alloc((size_t)1024 * 5120 * 2);  // [N=1024, K=5120]
  unsigned short* cat    = (unsigned short*)alloc(M * 5120 * 2);             // [h | av]
  unsigned short* qb     = (unsigned short*)alloc(M * 1024 * 2);
  unsigned short* kb     = (unsigned short*)alloc(M * 1024 * 2);
  unsigned short* vb     = (unsigned short*)alloc(M * 1024 * 2);

  // fused transposes + rmsnorm (independent; both feed gemm6)
  prep_all<<<dim3(20480), 256, 0, stream>>>(
      w_mlp_in, wq, wk, wv, w_mlp_out, w_attn_out, x, pns, wcatT, wcat2T, xn);

  // fused input GEMM: [8192,1024] x [7168,1024]^T; 128x128 tiles,
  // grid 56x64 = 3584 blocks; msplit=2 nsplit=4 (tn=14)
  gemm_bt<6><<<dim3(56, 64), 256, 0, stream>>>(
      xn, wcatT, 1024, cat, nullptr, nullptr, nullptr, 2, 32, 14, qb, kb, vb);

  flash_attn<<<dim3(16, 64), 256, 0, stream>>>(qb, kb, vb, cat);

  // fused output GEMM: [8192,5120] x [1024,5120]^T; 128x128 tiles,
  // grid 8x64 = 512 blocks; msplit=2 nsplit=4 (tn=2)
  gemm_bt<7><<<dim3(8, 64), 256, 0, stream>>>(
      cat, wcat2T, 5120, out, b_mlp_out, b_attn_out, x, 2, 32, 2, nullptr, nullptr, nullptr);
}